// Round 9
// baseline (478.241 us; speedup 1.0000x reference)
//
#include <hip/hip_runtime.h>
#include <hip/hip_bf16.h>
#include <cstdint>

// Problem constants
#define B_   2
#define S_   512
#define N_   20000
#define H_   3
#define C_   128
#define E_   320000
#define DG_  128
#define D_   384
#define BN_  (B_ * N_)            // 40000
#define F_   (H_ * C_)            // 384
#define ETOT_ (B_ * E_ + BN_)     // 680000

#define MPADQ 20096               // N_ padded to 128

// split-K for proj GEMM (K = N_ = 20000)
#define PNS 20
#define PCHUNK 1024

using short8  = __attribute__((ext_vector_type(8))) short;
using floatx4 = __attribute__((ext_vector_type(4))) float;

__device__ __forceinline__ float b2f(unsigned short u) {
  union { unsigned int i; float f; } x; x.i = ((unsigned int)u) << 16; return x.f;
}
__device__ __forceinline__ unsigned short f2b(float f) {
  __hip_bfloat16 b = __float2bfloat16(f);
  return *reinterpret_cast<unsigned short*>(&b);
}

// ================= conversion kernels =================
struct bf4 { __hip_bfloat16 a, b, c, d; };

__global__ __launch_bounds__(256) void conv_wq_kernel(const float* __restrict__ Wq,
                                                      __hip_bfloat16* __restrict__ o) {
  int idx = blockIdx.x * 256 + threadIdx.x;   // over MPADQ*512/4
  if (idx >= (MPADQ * 512) / 4) return;
  int e = idx * 4;
  int row = e >> 9;
  float4 v = make_float4(0.f, 0.f, 0.f, 0.f);
  if (row < N_) v = *(const float4*)(Wq + e);
  bf4 r{__float2bfloat16(v.x), __float2bfloat16(v.y),
        __float2bfloat16(v.z), __float2bfloat16(v.w)};
  *(bf4*)(o + e) = r;
}

// fused straight fp32->bf16 conversions: Wlin, Wproj, xe
#define NW4 (F_ * D_ / 4)                 // 36864
#define NP4 (S_ * N_ / 4)                 // 2,560,000
#define NX4 (B_ * S_ * D_ / 4)            // 98304
__global__ __launch_bounds__(256) void conv_misc_kernel(
    const float* __restrict__ Wlin, const float* __restrict__ Wproj,
    const float* __restrict__ xe, __hip_bfloat16* __restrict__ WlinB,
    __hip_bfloat16* __restrict__ WprojB, __hip_bfloat16* __restrict__ xeB) {
  int idx = blockIdx.x * 256 + threadIdx.x;
  const float* src; __hip_bfloat16* dst; int e;
  if (idx < NW4) { src = Wlin; dst = WlinB; e = idx * 4; }
  else if (idx < NW4 + NP4) { src = Wproj; dst = WprojB; e = (idx - NW4) * 4; }
  else if (idx < NW4 + NP4 + NX4) { src = xe; dst = xeB; e = (idx - NW4 - NP4) * 4; }
  else return;
  float4 v = *(const float4*)(src + e);
  bf4 r{__float2bfloat16(v.x), __float2bfloat16(v.y),
        __float2bfloat16(v.z), __float2bfloat16(v.w)};
  *(bf4*)(dst + e) = r;
}

// wlsum[f] = sum_d Wlin[f,d]; wlwm[f] = sum_d Wlin[f,d]*Wm[d]; wlbm[f] = sum_d Wlin[f,d]*bm[d]
__global__ __launch_bounds__(384) void prep_vec_kernel(
    const float* __restrict__ Wlin, const float* __restrict__ Wm,
    const float* __restrict__ bm, float* __restrict__ wlsum,
    float* __restrict__ wlwm, float* __restrict__ wlbm) {
  int f = threadIdx.x;
  const float* w = Wlin + (size_t)f * D_;
  float s0 = 0.f, s1 = 0.f, s2 = 0.f;
  for (int d = 0; d < D_; d += 4) {
    float4 wv = *(const float4*)(w + d);
    float4 wmv = *(const float4*)(Wm + d);
    float4 bmv = *(const float4*)(bm + d);
    s0 += wv.x + wv.y + wv.z + wv.w;
    s1 += wv.x * wmv.x + wv.y * wmv.y + wv.z * wmv.z + wv.w * wmv.w;
    s2 += wv.x * bmv.x + wv.y * bmv.y + wv.z * bmv.z + wv.w * bmv.w;
  }
  wlsum[f] = s0; wlwm[f] = s1; wlbm[f] = s2;
}

// ================= bf16 MFMA GEMM (NT: A[m][k], Bt[n][k], both k-major) =================
// MODE 1: xp epilogue (rank-1 bias terms), row-major store.
// MODE 2: plain accumulate, TRANSPOSED store C[cg*S_ + rg]  (for xeWT).
template <int MODE>
__global__ __launch_bounds__(256) void mfma_gemm_nt(
    const __hip_bfloat16* __restrict__ A, const __hip_bfloat16* __restrict__ Bt,
    __hip_bfloat16* __restrict__ Cout, int K, int Mvalid,
    size_t bstrideA, size_t bstrideB, size_t bstrideC,
    const float* __restrict__ bq, const float* __restrict__ mask,
    const float* __restrict__ wlsum, const float* __restrict__ wlwm,
    const float* __restrict__ wlbm) {
  const int tid = threadIdx.x;
  const int m0 = blockIdx.x * 128;
  const int n0 = blockIdx.y * 128;
  const int bz = blockIdx.z;

  const unsigned short* Ap = (const unsigned short*)(A + bstrideA * bz);
  const unsigned short* Bp = (const unsigned short*)(Bt + bstrideB * bz);

  __shared__ __align__(16) unsigned short As[128][40];
  __shared__ __align__(16) unsigned short Bs[128][40];

  const int wave = tid >> 6, lane = tid & 63;
  const int wm = (wave & 1) * 64, wn = (wave >> 1) * 64;
  const int lrow = lane & 15, lk = (lane >> 4) * 8;

  const int srow = tid >> 2;            // 0..63
  const int skoff = (tid & 3) * 8;      // 0,8,16,24

  floatx4 acc[4][4];
#pragma unroll
  for (int i = 0; i < 4; ++i)
#pragma unroll
    for (int j = 0; j < 4; ++j) acc[i][j] = floatx4{0.f, 0.f, 0.f, 0.f};

  for (int k0 = 0; k0 < K; k0 += 32) {
    int4 av0 = *(const int4*)(Ap + (size_t)(m0 + srow) * K + k0 + skoff);
    int4 av1 = *(const int4*)(Ap + (size_t)(m0 + 64 + srow) * K + k0 + skoff);
    int4 bv0 = *(const int4*)(Bp + (size_t)(n0 + srow) * K + k0 + skoff);
    int4 bv1 = *(const int4*)(Bp + (size_t)(n0 + 64 + srow) * K + k0 + skoff);
    __syncthreads();
    *(int4*)&As[srow][skoff] = av0;
    *(int4*)&As[64 + srow][skoff] = av1;
    *(int4*)&Bs[srow][skoff] = bv0;
    *(int4*)&Bs[64 + srow][skoff] = bv1;
    __syncthreads();
    short8 af[4], bf[4];
#pragma unroll
    for (int mt = 0; mt < 4; ++mt)
      af[mt] = *(const short8*)&As[wm + mt * 16 + lrow][lk];
#pragma unroll
    for (int nt = 0; nt < 4; ++nt)
      bf[nt] = *(const short8*)&Bs[wn + nt * 16 + lrow][lk];
#pragma unroll
    for (int mt = 0; mt < 4; ++mt)
#pragma unroll
      for (int nt = 0; nt < 4; ++nt)
        acc[mt][nt] = __builtin_amdgcn_mfma_f32_16x16x32_bf16(af[mt], bf[nt],
                                                              acc[mt][nt], 0, 0, 0);
  }

  __hip_bfloat16* Cb = Cout + bstrideC * bz;
#pragma unroll
  for (int mt = 0; mt < 4; ++mt) {
#pragma unroll
    for (int r = 0; r < 4; ++r) {
      int rg = m0 + wm + mt * 16 + (lane >> 4) * 4 + r;
      if (rg < Mvalid) {
        float bqv = 0.f, mkv = 0.f;
        if (MODE == 1) {
          bqv = bq[rg];
          mkv = mask[bz * N_ + rg];
        }
#pragma unroll
        for (int nt = 0; nt < 4; ++nt) {
          int cg = n0 + wn + nt * 16 + lrow;
          float v = acc[mt][nt][r];
          if (MODE == 1) {
            v += bqv * wlsum[cg] + mkv * wlwm[cg] + wlbm[cg];
            Cb[(size_t)rg * F_ + cg] = __float2bfloat16(v);
          } else {
            Cb[(size_t)cg * S_ + rg] = __float2bfloat16(v);
          }
        }
      }
    }
  }
}

// ================= proj GEMM: split-K bf16 MFMA, fp32 partial output =================
__global__ __launch_bounds__(256) void gemm_proj_mfma(
    const __hip_bfloat16* __restrict__ A, const __hip_bfloat16* __restrict__ Bt,
    float* __restrict__ Ppart) {
  const int tid = threadIdx.x;
  const int m0 = blockIdx.x * 128;       // s
  const int n0 = blockIdx.y * 128;       // f
  const int bz = blockIdx.z;             // b*PNS + ks
  const int b = bz / PNS, ks = bz - b * PNS;
  const int kbeg = ks * PCHUNK;
  const int kend = (kbeg + PCHUNK < N_) ? (kbeg + PCHUNK) : N_;

  const unsigned short* Ap = (const unsigned short*)A;
  const unsigned short* Bp = (const unsigned short*)(Bt + (size_t)b * F_ * N_);

  __shared__ __align__(16) unsigned short As[128][40];
  __shared__ __align__(16) unsigned short Bs[128][40];

  const int wave = tid >> 6, lane = tid & 63;
  const int wm = (wave & 1) * 64, wn = (wave >> 1) * 64;
  const int lrow = lane & 15, lk = (lane >> 4) * 8;
  const int srow = tid >> 2;
  const int skoff = (tid & 3) * 8;

  floatx4 acc[4][4];
#pragma unroll
  for (int i = 0; i < 4; ++i)
#pragma unroll
    for (int j = 0; j < 4; ++j) acc[i][j] = floatx4{0.f, 0.f, 0.f, 0.f};

  for (int k0 = kbeg; k0 < kend; k0 += 32) {
    int4 av0 = *(const int4*)(Ap + (size_t)(m0 + srow) * N_ + k0 + skoff);
    int4 av1 = *(const int4*)(Ap + (size_t)(m0 + 64 + srow) * N_ + k0 + skoff);
    int4 bv0 = *(const int4*)(Bp + (size_t)(n0 + srow) * N_ + k0 + skoff);
    int4 bv1 = *(const int4*)(Bp + (size_t)(n0 + 64 + srow) * N_ + k0 + skoff);
    __syncthreads();
    *(int4*)&As[srow][skoff] = av0;
    *(int4*)&As[64 + srow][skoff] = av1;
    *(int4*)&Bs[srow][skoff] = bv0;
    *(int4*)&Bs[64 + srow][skoff] = bv1;
    __syncthreads();
    short8 af[4], bf[4];
#pragma unroll
    for (int mt = 0; mt < 4; ++mt)
      af[mt] = *(const short8*)&As[wm + mt * 16 + lrow][lk];
#pragma unroll
    for (int nt = 0; nt < 4; ++nt)
      bf[nt] = *(const short8*)&Bs[wn + nt * 16 + lrow][lk];
#pragma unroll
    for (int mt = 0; mt < 4; ++mt)
#pragma unroll
      for (int nt = 0; nt < 4; ++nt)
        acc[mt][nt] = __builtin_amdgcn_mfma_f32_16x16x32_bf16(af[mt], bf[nt],
                                                              acc[mt][nt], 0, 0, 0);
  }

  float* Pp = Ppart + (size_t)bz * S_ * F_;
#pragma unroll
  for (int mt = 0; mt < 4; ++mt) {
#pragma unroll
    for (int r = 0; r < 4; ++r) {
      int rg = m0 + wm + mt * 16 + (lane >> 4) * 4 + r;
#pragma unroll
      for (int nt = 0; nt < 4; ++nt) {
        int cg = n0 + wn + nt * 16 + lrow;
        Pp[(size_t)rg * F_ + cg] = acc[mt][nt][r];
      }
    }
  }
}

// ================= transpose gat [b][N][F] bf16 -> gatT [b][F][N] bf16 =================
#define TT 64
__global__ __launch_bounds__(256) void transpose_kernel(
    const __hip_bfloat16* __restrict__ in, __hip_bfloat16* __restrict__ out) {
  __shared__ unsigned short tile[TT][TT + 8];
  int n0 = blockIdx.x * TT, f0 = blockIdx.y * TT, b = blockIdx.z;
  int t = threadIdx.x;
  const unsigned short* ip = (const unsigned short*)(in + (size_t)b * N_ * F_);
  unsigned short* op = (unsigned short*)(out + (size_t)b * F_ * N_);
  int fo = (t & 7) * 8, ro = t >> 3;  // ro 0..31
#pragma unroll
  for (int half = 0; half < 2; ++half) {
    int r = ro + half * 32;
    if (n0 + r < N_)
      *(int4*)&tile[r][fo] = *(const int4*)(ip + (size_t)(n0 + r) * F_ + f0 + fo);
    else
      *(int4*)&tile[r][fo] = make_int4(0, 0, 0, 0);
  }
  __syncthreads();
  int no = (t & 7) * 8, fo2 = t >> 3;
  if (n0 + no + 8 <= N_) {
#pragma unroll
    for (int half = 0; half < 2; ++half) {
      int f = fo2 + half * 32;
      unsigned short v[8];
#pragma unroll
      for (int j = 0; j < 8; ++j) v[j] = tile[no + j][f];
      *(int4*)(op + (size_t)(f0 + f) * N_ + n0 + no) = *(int4*)v;
    }
  }
}

// ---------------- attention coefficients ----------------
__global__ __launch_bounds__(256) void att_kernel(
    const __hip_bfloat16* __restrict__ xp, const float* __restrict__ att_src,
    const float* __restrict__ att_dst, float* __restrict__ a_src,
    float* __restrict__ a_dst) {
  int gid = blockIdx.x * blockDim.x + threadIdx.x;
  int wid = gid >> 6;
  int lane = threadIdx.x & 63;
  if (wid >= BN_ * H_) return;
  int i = wid / H_, h = wid - i * H_;
  const __hip_bfloat16* row = xp + (size_t)i * F_ + h * C_;
  const float* as = att_src + h * C_;
  const float* ad = att_dst + h * C_;
  float v0 = __bfloat162float(row[lane]), v1 = __bfloat162float(row[lane + 64]);
  float s1 = v0 * as[lane] + v1 * as[lane + 64];
  float s2 = v0 * ad[lane] + v1 * ad[lane + 64];
#pragma unroll
  for (int off = 32; off > 0; off >>= 1) {
    s1 += __shfl_down(s1, off);
    s2 += __shfl_down(s2, off);
  }
  if (lane == 0) {
    a_src[i * H_ + h] = s1;
    a_dst[i * H_ + h] = s2;
  }
}

// ---------------- CSR build ----------------
__global__ __launch_bounds__(256) void count_kernel(const int* __restrict__ ei,
                                                    int* __restrict__ counts,
                                                    int* __restrict__ rank) {
  int idx = blockIdx.x * blockDim.x + threadIdx.x;
  if (idx >= 2 * E_) return;
  int b = (idx >= E_) ? 1 : 0;
  int e = idx - b * E_;
  int d = ei[E_ + e];
  rank[idx] = atomicAdd(&counts[b * N_ + d], 1);
}

// single-block shuffle-based exclusive scan of (counts[i]+1)  [round-7 proven version]
__global__ __launch_bounds__(1024) void scan_kernel(const int* __restrict__ counts,
                                                    int* __restrict__ offs) {
  __shared__ int wsum[16];
  __shared__ int carry;
  int t = threadIdx.x, wave = t >> 6, lane = t & 63;
  if (t == 0) carry = 0;
  __syncthreads();
  for (int base = 0; base < BN_; base += 1024) {
    int i = base + t;
    int v = (i < BN_) ? (counts[i] + 1) : 0;  // +1 = self loop
    int x = v;
#pragma unroll
    for (int o = 1; o < 64; o <<= 1) {
      int y = __shfl_up(x, o);
      if (lane >= o) x += y;
    }
    if (lane == 63) wsum[wave] = x;
    __syncthreads();
    int c = carry;
    if (wave == 0) {
      int w = (lane < 16) ? wsum[lane] : 0;
#pragma unroll
      for (int o = 1; o < 16; o <<= 1) {
        int y = __shfl_up(w, o);
        if (lane >= o) w += y;
      }
      if (lane < 16) wsum[lane] = w;
    }
    __syncthreads();
    int woff = (wave == 0) ? 0 : wsum[wave - 1];
    int excl = c + woff + x - v;
    if (i < BN_) offs[i] = excl;
    int total = wsum[15];
    __syncthreads();
    if (t == 0) carry = c + total;
  }
}

// fill CSR col — NO atomics: pos = offs[dst] + rank[edge]; self-loop at offs[i]+counts[i]
__global__ __launch_bounds__(256) void fill_kernel(
    const int* __restrict__ ei, const int* __restrict__ rank,
    const int* __restrict__ offs, const int* __restrict__ counts,
    int* __restrict__ col) {
  int idx = blockIdx.x * blockDim.x + threadIdx.x;
  if (idx >= ETOT_) return;
  if (idx < 2 * E_) {
    int b = (idx >= E_) ? 1 : 0;
    int e = idx - b * E_;
    int sg = b * N_ + ei[e];
    int dg = b * N_ + ei[E_ + e];
    col[offs[dg] + rank[idx]] = sg;
  } else {
    int i = idx - 2 * E_;
    col[offs[i] + counts[i]] = i;
  }
}

// ---------------- per-node softmax denominators (wave per node) ----------------
__global__ __launch_bounds__(256) void denom_kernel(
    const int* __restrict__ offs, const int* __restrict__ counts,
    const int* __restrict__ col, const float* __restrict__ a_src,
    const float* __restrict__ a_dst, float4* __restrict__ rden4) {
  int i = (blockIdx.x * 256 + threadIdx.x) >> 6;   // global wave id = node
  int lane = threadIdx.x & 63;
  if (i >= BN_) return;                            // wave-uniform
  int beg = offs[i], nE = counts[i] + 1;
  float ad0 = a_dst[i * 3 + 0], ad1 = a_dst[i * 3 + 1], ad2 = a_dst[i * 3 + 2];
  float d0 = 0.f, d1 = 0.f, d2 = 0.f;
  for (int j = lane; j < nE; j += 64) {
    int s = col[beg + j];
    float e0 = a_src[s * 3 + 0] + ad0;
    float e1 = a_src[s * 3 + 1] + ad1;
    float e2 = a_src[s * 3 + 2] + ad2;
    e0 = (e0 > 0.f) ? e0 : 0.2f * e0;
    e1 = (e1 > 0.f) ? e1 : 0.2f * e1;
    e2 = (e2 > 0.f) ? e2 : 0.2f * e2;
    d0 += __expf(e0); d1 += __expf(e1); d2 += __expf(e2);
  }
#pragma unroll
  for (int o = 32; o > 0; o >>= 1) {
    d0 += __shfl_down(d0, o);
    d1 += __shfl_down(d1, o);
    d2 += __shfl_down(d2, o);
  }
  if (lane == 0) rden4[i] = make_float4(1.0f / d0, 1.0f / d1, 1.0f / d2, 0.f);
}

// ---------------- aggregation: 128 threads; 96 gather ushort4, 32 stage ----------------
#define ACHK 32
__global__ __launch_bounds__(128) void agg_kernel(
    const int* __restrict__ offs, const int* __restrict__ counts,
    const int* __restrict__ col, const float* __restrict__ a_src,
    const float* __restrict__ a_dst, const float4* __restrict__ rden4,
    const __hip_bfloat16* __restrict__ xp,
    const float* __restrict__ bias_gat, __hip_bfloat16* __restrict__ out) {
  int i = blockIdx.x;
  int t = threadIdx.x;
  int beg = offs[i];
  int nE = counts[i] + 1;
  __shared__ int scol[ACHK];
  __shared__ float sexp[ACHK][4];

  const ushort4* xp4 = (const ushort4*)xp;   // row stride 96 ushort4
  int h = t >> 5;                            // head for gather threads (t<96)
  float ax = 0.f, ay = 0.f, az = 0.f, aw = 0.f;
  float ad0 = 0.f, ad1 = 0.f, ad2 = 0.f;
  if (t >= 96) {
    ad0 = a_dst[i * 3 + 0]; ad1 = a_dst[i * 3 + 1]; ad2 = a_dst[i * 3 + 2];
  }

  for (int c0 = 0; c0 < nE; c0 += ACHK) {
    int cn = min(ACHK, nE - c0);
    __syncthreads();
    int ts = t - 96;
    if (ts >= 0 && ts < cn) {
      int s = col[beg + c0 + ts];
      scol[ts] = s;
      float e0 = a_src[s * 3 + 0] + ad0;
      float e1 = a_src[s * 3 + 1] + ad1;
      float e2 = a_src[s * 3 + 2] + ad2;
      e0 = (e0 > 0.f) ? e0 : 0.2f * e0;
      e1 = (e1 > 0.f) ? e1 : 0.2f * e1;
      e2 = (e2 > 0.f) ? e2 : 0.2f * e2;
      sexp[ts][0] = __expf(e0);
      sexp[ts][1] = __expf(e1);
      sexp[ts][2] = __expf(e2);
    }
    __syncthreads();
    if (t < 96) {
      int j = 0;
      for (; j + 4 <= cn; j += 4) {
        int s0 = scol[j + 0], s1 = scol[j + 1], s2 = scol[j + 2], s3 = scol[j + 3];
        ushort4 v0 = xp4[(size_t)s0 * 96 + t];
        ushort4 v1 = xp4[(size_t)s1 * 96 + t];
        ushort4 v2 = xp4[(size_t)s2 * 96 + t];
        ushort4 v3 = xp4[(size_t)s3 * 96 + t];
        float w0 = sexp[j + 0][h], w1 = sexp[j + 1][h];
        float w2 = sexp[j + 2][h], w3 = sexp[j + 3][h];
        ax = fmaf(w0, b2f(v0.x), ax); ay = fmaf(w0, b2f(v0.y), ay);
        az = fmaf(w0, b2f(v0.z), az); aw = fmaf(w0, b2f(v0.w), aw);
        ax = fmaf(w1, b2f(v1.x), ax); ay = fmaf(w1, b2f(v1.y), ay);
        az = fmaf(w1, b2f(v1.z), az); aw = fmaf(w1, b2f(v1.w), aw);
        ax = fmaf(w2, b2f(v2.x), ax); ay = fmaf(w2, b2f(v2.y), ay);
        az = fmaf(w2, b2f(v2.z), az); aw = fmaf(w2, b2f(v2.w), aw);
        ax = fmaf(w3, b2f(v3.x), ax); ay = fmaf(w3, b2f(v3.y), ay);
        az = fmaf(w3, b2f(v3.z), az); aw = fmaf(w3, b2f(v3.w), aw);
      }
      for (; j < cn; ++j) {
        int s0 = scol[j];
        ushort4 v0 = xp4[(size_t)s0 * 96 + t];
        float w0 = sexp[j][h];
        ax = fmaf(w0, b2f(v0.x), ax); ay = fmaf(w0, b2f(v0.y), ay);
        az = fmaf(w0, b2f(v0.z), az); aw = fmaf(w0, b2f(v0.w), aw);
      }
    }
  }
  if (t < 96) {
    float4 rd = rden4[i];
    float r = (h == 0) ? rd.x : ((h == 1) ? rd.y : rd.z);
    const float4 bg = *(const float4*)(bias_gat + t * 4);
    ushort4 o;
    o.x = f2b(ax * r + bg.x);
    o.y = f2b(ay * r + bg.y);
    o.z = f2b(az * r + bg.z);
    o.w = f2b(aw * r + bg.w);
    *(ushort4*)((unsigned short*)out + (size_t)i * F_ + t * 4) = o;
  }
}

// ---------------- GEMM 4: reduce split-K partials + temp projection ----------------
__global__ __launch_bounds__(128) void temp_kernel(
    const float* __restrict__ Ppart, const float* __restrict__ bproj,
    const float* __restrict__ Wtemp, const float* __restrict__ btemp,
    float* __restrict__ out) {
  int bs = blockIdx.x;          // 0..B*S-1
  int b = bs >> 9;
  int s = bs & (S_ - 1);
  int g = threadIdx.x;
  __shared__ float prow[F_];
  float bp = bproj[s];
  for (int f = g; f < F_; f += 128) {
    float acc = bp;
    const float* pp = Ppart + ((size_t)b * PNS * S_ + s) * F_ + f;
    for (int ns = 0; ns < PNS; ++ns) acc += pp[(size_t)ns * S_ * F_];
    prow[f] = acc;
  }
  __syncthreads();
  float acc = btemp[g];
  const float* w = Wtemp + (size_t)g * F_;
  for (int f = 0; f < F_; f += 4) {
    float4 pv = *(const float4*)&prow[f];
    float4 wv = *(const float4*)&w[f];
    acc += pv.x * wv.x + pv.y * wv.y + pv.z * wv.z + pv.w * wv.w;
  }
  out[(size_t)bs * DG_ + g] = acc;
}

// ---------------- launcher ----------------
extern "C" void kernel_launch(void* const* d_in, const int* in_sizes, int n_in,
                              void* d_out, int out_size, void* d_ws, size_t ws_size,
                              hipStream_t stream) {
  const float* x_enc   = (const float*)d_in[0];
  const float* mask    = (const float*)d_in[1];
  const int*   ei      = (const int*)d_in[2];
  const float* Wq      = (const float*)d_in[3];
  const float* bq      = (const float*)d_in[4];
  const float* Wm      = (const float*)d_in[5];
  const float* bm      = (const float*)d_in[6];
  const float* Wlin    = (const float*)d_in[7];
  const float* att_src = (const float*)d_in[8];
  const float* att_dst = (const float*)d_in[9];
  const float* bias_gat= (const float*)d_in[10];
  const float* Wproj   = (const float*)d_in[11];
  const float* bproj   = (const float*)d_in[12];
  const float* Wtemp   = (const float*)d_in[13];
  const float* btemp   = (const float*)d_in[14];
  float* outp = (float*)d_out;

  char* ws = (char*)d_ws;
  size_t off = 0;
  auto alloc = [&](size_t bytes) {
    char* p = ws + off;
    off = (off + bytes + 255) & ~(size_t)255;
    return p;
  };

  // regionA timeline:
  //   phase 1 (conv/mini-gemm/gemm_q): Wq_b (20.6M) + xeB (0.79M) + xeWT (0.79M)
  //   phase 2 (agg):                   gat bf16 at 0..30.7M
  //   phase 3 (transpose):             gatT at 31.46..62.2M (reads gat)
  //   phase 4 (gemm_proj):             Ppart fp32 at 0..31.46M (reads gatT)
  const size_t GATT_OFF = 31457536;  // > Ppart end (31,457,280), 256-aligned
  char* regionA = alloc(GATT_OFF + (size_t)B_ * F_ * N_ * 2);   // 62.2 MB
  __hip_bfloat16* Wq_b = (__hip_bfloat16*)regionA;
  __hip_bfloat16* xeB  = (__hip_bfloat16*)(regionA + (size_t)MPADQ * S_ * 2);
  __hip_bfloat16* xeWT = (__hip_bfloat16*)(regionA + (size_t)MPADQ * S_ * 2
                                                   + (size_t)B_ * S_ * D_ * 2);
  __hip_bfloat16* gat  = (__hip_bfloat16*)regionA;
  __hip_bfloat16* gatT = (__hip_bfloat16*)(regionA + GATT_OFF);
  float* Ppart = (float*)regionA;

  __hip_bfloat16* xp     = (__hip_bfloat16*)alloc((size_t)BN_ * F_ * 2);
  __hip_bfloat16* WlinB  = (__hip_bfloat16*)alloc((size_t)F_ * D_ * 2);
  __hip_bfloat16* WprojB = (__hip_bfloat16*)alloc((size_t)S_ * N_ * 2);
  float* a_src = (float*)alloc((size_t)BN_ * H_ * 4);
  float* a_dst = (float*)alloc((size_t)BN_ * H_ * 4);
  int* counts  = (int*)alloc((size_t)BN_ * 4);
  int* offsb   = (int*)alloc((size_t)BN_ * 4);
  int* rank    = (int*)alloc((size_t)2 * E_ * 4);
  int* col     = (int*)alloc((size_t)ETOT_ * 4);
  float4* rden4 = (float4*)alloc((size_t)BN_ * 16);
  float* wlsum = (float*)alloc((size_t)F_ * 4);
  float* wlwm  = (float*)alloc((size_t)F_ * 4);
  float* wlbm  = (float*)alloc((size_t)F_ * 4);
  if (off > ws_size) return;  // workspace too small: fail loudly via absmax

  hipMemsetAsync(counts, 0, (size_t)BN_ * 4, stream);

  // CSR skeleton (independent of everything else)
  count_kernel<<<(2 * E_ + 255) / 256, 256, 0, stream>>>(ei, counts, rank);
  scan_kernel<<<1, 1024, 0, stream>>>(counts, offsb);
  fill_kernel<<<(ETOT_ + 255) / 256, 256, 0, stream>>>(ei, rank, offsb, counts, col);

  // conversions + epilogue-vector precompute
  conv_wq_kernel<<<(MPADQ * S_ / 4 + 255) / 256, 256, 0, stream>>>(Wq, Wq_b);
  conv_misc_kernel<<<(NW4 + NP4 + NX4 + 255) / 256, 256, 0, stream>>>(
      Wlin, Wproj, x_enc, WlinB, WprojB, xeB);
  prep_vec_kernel<<<1, 384, 0, stream>>>(Wlin, Wm, bm, wlsum, wlwm, wlbm);

  // mini-GEMM: xeWT[b][f][s] = (xe·Wlin^T)^T   (M=S, N=F, K=D; transposed store)
  mfma_gemm_nt<2><<<dim3(S_ / 128, F_ / 128, B_), 256, 0, stream>>>(
      xeB, WlinB, xeWT, D_, S_, (size_t)S_ * D_, 0, (size_t)F_ * S_,
      nullptr, nullptr, nullptr, nullptr, nullptr);

  // gemm_q': xp[b,n,f] = sum_s Wq[n,s]·xeWT[b,f,s] + bq[n]·wlsum[f] + mask·wlwm[f] + wlbm[f]
  mfma_gemm_nt<1><<<dim3(MPADQ / 128, F_ / 128, B_), 256, 0, stream>>>(
      Wq_b, xeWT, xp, S_, N_, 0, (size_t)F_ * S_, (size_t)N_ * F_,
      bq, mask, wlsum, wlwm, wlbm);

  att_kernel<<<(BN_ * H_ + 3) / 4, 256, 0, stream>>>(xp, att_src, att_dst, a_src, a_dst);
  denom_kernel<<<BN_ / 4, 256, 0, stream>>>(offsb, counts, col, a_src, a_dst, rden4);
  agg_kernel<<<BN_, 128, 0, stream>>>(offsb, counts, col, a_src, a_dst, rden4,
                                      xp, bias_gat, gat);
  transpose_kernel<<<dim3((N_ + TT - 1) / TT, F_ / TT, B_), 256, 0, stream>>>(gat, gatT);
  gemm_proj_mfma<<<dim3(S_ / 128, F_ / 128, B_ * PNS), 256, 0, stream>>>(WprojB, gatT, Ppart);
  temp_kernel<<<B_ * S_, 128, 0, stream>>>(Ppart, bproj, Wtemp, btemp, outp);
}